// Round 5
// baseline (333.973 us; speedup 1.0000x reference)
//
#include <hip/hip_runtime.h>

// AnalyticalBoundedLineAttractor — exact linear-regime stepping via Taylor
// recurrence:
//   z = Wx + b; m_dt = (z>0)?dt:0
//   w1 = m_dt*z - dt*x;  wk = (m_dt*(W w) - dt*w)/k;  x+ = x + sum wk
// ||Z|| <= dt*(||W||_2+1) ~ 0.15 -> K=3 terms, local truncation ~2e-5/step,
// accumulated ~6e-3 (threshold 7.7e-2; non-expansive dynamics, no blowup).
//
// History:
//   R0 (readlane, 1 chain/wave): 65.5 us. Issue model fit: v_readlane ~6 cyc.
//   R1 (LDS write->wait->read): 124 us. Round-trip latency serializes. Revert.
//   R2 (2 chains/wave): 127.7 us = exactly 2x per-wave work -> ISSUE-BOUND,
//     no fillable stalls; VGPR=76 proved Wr residency is not the lever.
//   R3: DS-crossbar broadcast — failed to COMPILE (ds_swizzle offset must be
//     an integer constant; unrolled loop var doesn't qualify).
//   R4 (this): same algorithm, swizzle offsets generated via template
//     recursion so every __builtin_amdgcn_ds_swizzle gets a literal.
//     wx = bpermute(w, lane^32); y_lo = lane<32?w:wx (= w[lane&31]),
//     y_hi = mirror (= w[32|(lane&31)]). Slot j for ALL lanes is ONE
//     ds_swizzle(y_lo/y_hi, BitMode and=0,or=0,xor=j) -> src lane j within
//     each 32-half, and y_* maps both halves to w_j / w_{32+j}.
//     65 DS ops (~2.5-3 cyc issue) + 64 FMA vs 64x6-cyc readlane.
//     FMA accumulation order/values BITWISE IDENTICAL to R0 -> absmax
//     stays 0.015625.

#define DT_F 0.05f
#define T_STEPS 100
#define DD 64
#define KT 3      // Taylor terms w_1..w_KT
#define BATCH_MAX 256

// Emit sz[J] = w[J] and sz[32+J] = w[32+J] broadcasts with literal offsets.
template <int J>
__device__ __forceinline__ void swz_bcast(int ylo, int yhi, int (&sz)[DD]) {
    // offset = xor<<10 | or<<5 | and; and=0, or=0, xor=J (BitMode, bit15=0)
    sz[J]      = __builtin_amdgcn_ds_swizzle(ylo, (J << 10));
    sz[32 + J] = __builtin_amdgcn_ds_swizzle(yhi, (J << 10));
    if constexpr (J < 31) swz_bcast<J + 1>(ylo, yhi, sz);
}

// Broadcast-matvec via DS crossbar. Lane i holds row i of W (natural order).
// Two-phase: issue all 64 swizzle broadcasts (DS pipe, pipelined), then 64
// FMAs in R0's exact grouping.
__device__ __forceinline__ float matvec_sw(const float (&Wr)[DD], float w,
                                           int bpidx, bool lo_half) {
    const int wi = __float_as_int(w);
    // w[lane^32]: one cross-half route (index is lane-varying -> no fold).
    const int wxi = __builtin_amdgcn_ds_bpermute(bpidx, wi);
    const int ylo = lo_half ? wi : wxi;   // y_lo[i] = w[i & 31]
    const int yhi = lo_half ? wxi : wi;   // y_hi[i] = w[32 | (i & 31)]

    int sz[DD];
    swz_bcast<0>(ylo, yhi, sz);

    float a0 = 0.f, a1 = 0.f, a2 = 0.f, a3 = 0.f;
#pragma unroll
    for (int j = 0; j < DD; j += 4) {
        a0 = fmaf(Wr[j + 0], __int_as_float(sz[j + 0]), a0);
        a1 = fmaf(Wr[j + 1], __int_as_float(sz[j + 1]), a1);
        a2 = fmaf(Wr[j + 2], __int_as_float(sz[j + 2]), a2);
        a3 = fmaf(Wr[j + 3], __int_as_float(sz[j + 3]), a3);
    }
    return (a0 + a1) + (a2 + a3);
}

__global__ __launch_bounds__(64, 1)
void abla_kernel(const float* __restrict__ x0,
                 const float* __restrict__ W,
                 const float* __restrict__ bvec,
                 float* __restrict__ out) {
    const int batch = blockIdx.x;
    const int lane = threadIdx.x;

    // Lane i caches row i of W (natural order). Pinned to VGPRs below.
    float Wr[DD];
#pragma unroll
    for (int j = 0; j < DD; j += 4) {
        const float4 w4 = *reinterpret_cast<const float4*>(W + lane * DD + j);
        Wr[j + 0] = w4.x; Wr[j + 1] = w4.y; Wr[j + 2] = w4.z; Wr[j + 3] = w4.w;
    }
    const float bi = bvec[lane];
    const int bpidx = (lane ^ 32) << 2;   // byte index for ds_bpermute
    const bool lo_half = (lane < 32);
    float x = x0[batch * DD + lane];
    float* outp = out + (size_t)batch * T_STEPS * DD + lane;

    for (int t = 0; t < T_STEPS; ++t) {
        // Forbid rematerialization of the W row (emits no instructions).
#pragma unroll
        for (int j = 0; j < DD; ++j) asm volatile("" : "+v"(Wr[j]));

        // Trajectory stores the state BEFORE the update (off critical path).
        outp[(size_t)t * DD] = x;

        // term 1: z = Wx + b gives the regime mask
        const float z = matvec_sw(Wr, x, bpidx, lo_half) + bi;
        const float m_dt = (z > 0.f) ? DT_F : 0.f;
        float w = m_dt * z - DT_F * x;
        float y = x + w;

        // terms 2..KT
#pragma unroll
        for (int k = 2; k <= KT; ++k) {
            const float v = matvec_sw(Wr, w, bpidx, lo_half);
            w = (m_dt * v - DT_F * w) * (1.0f / (float)k);
            y += w;
        }
        x = y;
    }
}

extern "C" void kernel_launch(void* const* d_in, const int* in_sizes, int n_in,
                              void* d_out, int out_size, void* d_ws, size_t ws_size,
                              hipStream_t stream) {
    const float* x0 = (const float*)d_in[0];   // (256, 64) f32
    const float* W  = (const float*)d_in[1];   // (64, 64)  f32
    const float* b  = (const float*)d_in[2];   // (64,)     f32
    float* out = (float*)d_out;                // (256, 100, 64) f32

    // Problem shape is fixed (batch=256, dim=64). Derive batch from
    // in_sizes[0] when it is a plausible element count; clamp otherwise so a
    // bytes-vs-elements unit mismatch can never launch an OOB grid.
    int batch = in_sizes[0] / DD;
    if (batch <= 0 || batch > BATCH_MAX) batch = BATCH_MAX;
    abla_kernel<<<batch, DD, 0, stream>>>(x0, W, b, out);
}

// Round 6
// 133.039 us; speedup vs baseline: 2.5103x; 2.5103x over previous
//
#include <hip/hip_runtime.h>

// AnalyticalBoundedLineAttractor — Taylor stepping (K=3) as in R0, but the
// 64x64 matvec is done by MFMA for 16 chains at once (4 waves, one 16-wide
// n-tile each), eliminating the per-element broadcast that bounded R0.
//
// History:
//   R0 readlane 1-chain: 65.5us (issue-bound, readlane ~6cyc).
//   R1 LDS bcast: 124us (round-trip serialized). R2 2-chain: exactly 2x ->
//   issue-bound confirmed. R4 ds_swizzle: 281us (DS latency serialized).
//   => broadcast structure is a dead end; R5 moves the routing into MFMA.
//
// Correctness notes:
//   * C/D layout for mfma_f32_16x16x32_bf16 is HW-verified (m89):
//     col = lane&15, row = 4*(lane>>4) + reg. State lives at these positions.
//   * A and B fragments are BOTH loaded with the same assumed k-map
//     (k = 32ks + 16h + 4*(lane>>4) + e). MFMA pairs A/B slots with a shared
//     k-assignment, so any bijective error in the assumed map cancels.
//   * W is preloaded as bf16 hi+lo split (residual ~5e-7); the dynamic side
//     is single bf16: accumulated state error ~1e-2, threshold 7.7e-2.
//   * Double-buffered LDS + one {lgkmcnt(0); s_barrier} per matvec (asm with
//     memory clobber so LDS ops can't cross it). Trajectory stores are
//     fire-and-forget (vmcnt never drained in-loop).

#define DT_F 0.05f
#define T_STEPS 100
#define DD 64
#define BT 16            // batches (chains) per workgroup
#define PADK 68          // padded row length (shorts) -> conflict-free writes
#define BATCH_MAX 256

typedef __attribute__((ext_vector_type(8))) short bf16x8;
typedef __attribute__((ext_vector_type(4))) float f32x4;

__device__ __forceinline__ unsigned short f32_bf16(float f) {
    unsigned u = __float_as_uint(f);
    u += 0x7FFFu + ((u >> 16) & 1u);          // round-to-nearest-even
    return (unsigned short)(u >> 16);
}
__device__ __forceinline__ float bf16_f32(unsigned short h) {
    return __uint_as_float(((unsigned)h) << 16);
}

__global__ __launch_bounds__(256, 1)
void abla_kernel(const float* __restrict__ x0,
                 const float* __restrict__ W,
                 const float* __restrict__ bvec,
                 float* __restrict__ out) {
    const int wg = blockIdx.x;
    const int wv = threadIdx.x >> 6;   // wave id = n-tile (i-slice) 0..3
    const int l  = threadIdx.x & 63;
    const int lo = l & 15;             // m/n index within 16
    const int g  = l >> 4;             // lane group 0..3 (k-slice)

    __shared__ unsigned short wbuf[2][BT * PADK];

    // ---- B operand (static): B[k][n] = W^T[k][n] = W[n][k], n = 16*wv+lo.
    // frag short[4*h+e] = B[k = 32*ks + 16*h + 4*g + e][n]; hi+lo split.
    bf16x8 Bhi[2], Blo[2];
    {
        const float* wrow = W + (16 * wv + lo) * DD;
#pragma unroll
        for (int ks = 0; ks < 2; ++ks) {
#pragma unroll
            for (int h = 0; h < 2; ++h) {
                const float4 c = *reinterpret_cast<const float4*>(
                    wrow + ks * 32 + 16 * h + 4 * g);
                const float cf[4] = {c.x, c.y, c.z, c.w};
#pragma unroll
                for (int e = 0; e < 4; ++e) {
                    const unsigned short hi = f32_bf16(cf[e]);
                    const unsigned short lo16 = f32_bf16(cf[e] - bf16_f32(hi));
                    Bhi[ks][4 * h + e] = (short)hi;
                    Blo[ks][4 * h + e] = (short)lo16;
                }
            }
        }
    }

    const float bi = bvec[16 * wv + lo];

    // State x at C/D positions: value r <-> (b = 4*g + r, i = 16*wv + lo).
    float x[4];
    float* op[4];
#pragma unroll
    for (int r = 0; r < 4; ++r) {
        const int bg = wg * BT + 4 * g + r;
        x[r] = x0[bg * DD + 16 * wv + lo];
        op[r] = out + (size_t)bg * T_STEPS * DD + 16 * wv + lo;
    }

    int p = 0;  // LDS double-buffer selector (toggles every matvec)

    // matvec: publish v (this wave's i-slice of the vector) -> barrier ->
    // read shared A-fragments -> 4 MFMAs -> result at C positions.
    auto matvec = [&](const float v[4], f32x4& res) {
#pragma unroll
        for (int r = 0; r < 4; ++r)
            wbuf[p][(4 * g + r) * PADK + 16 * wv + lo] = f32_bf16(v[r]);
        asm volatile("s_waitcnt lgkmcnt(0)\n\ts_barrier" ::: "memory");
        const unsigned short* ab = &wbuf[p][lo * PADK + 4 * g];
        const ushort4 q00 = *reinterpret_cast<const ushort4*>(ab + 0);
        const ushort4 q01 = *reinterpret_cast<const ushort4*>(ab + 16);
        const ushort4 q10 = *reinterpret_cast<const ushort4*>(ab + 32);
        const ushort4 q11 = *reinterpret_cast<const ushort4*>(ab + 48);
        bf16x8 a0, a1;
        a0[0] = (short)q00.x; a0[1] = (short)q00.y;
        a0[2] = (short)q00.z; a0[3] = (short)q00.w;
        a0[4] = (short)q01.x; a0[5] = (short)q01.y;
        a0[6] = (short)q01.z; a0[7] = (short)q01.w;
        a1[0] = (short)q10.x; a1[1] = (short)q10.y;
        a1[2] = (short)q10.z; a1[3] = (short)q10.w;
        a1[4] = (short)q11.x; a1[5] = (short)q11.y;
        a1[6] = (short)q11.z; a1[7] = (short)q11.w;
        f32x4 acc0 = {0.f, 0.f, 0.f, 0.f};
        f32x4 acc1 = {0.f, 0.f, 0.f, 0.f};
        acc0 = __builtin_amdgcn_mfma_f32_16x16x32_bf16(a0, Bhi[0], acc0, 0, 0, 0);
        acc1 = __builtin_amdgcn_mfma_f32_16x16x32_bf16(a0, Blo[0], acc1, 0, 0, 0);
        acc0 = __builtin_amdgcn_mfma_f32_16x16x32_bf16(a1, Bhi[1], acc0, 0, 0, 0);
        acc1 = __builtin_amdgcn_mfma_f32_16x16x32_bf16(a1, Blo[1], acc1, 0, 0, 0);
        res = acc0 + acc1;
        p ^= 1;
    };

    float w[4], y[4], mdt[4];

    for (int t = 0; t < T_STEPS; ++t) {
        // Trajectory stores state BEFORE the update; fire-and-forget.
#pragma unroll
        for (int r = 0; r < 4; ++r) { op[r][0] = x[r]; op[r] += DD; }

        // term 1: z = Wx + b -> regime mask
        f32x4 z4;
        matvec(x, z4);
#pragma unroll
        for (int r = 0; r < 4; ++r) {
            const float z = z4[r] + bi;
            mdt[r] = (z > 0.f) ? DT_F : 0.f;
            w[r] = mdt[r] * z - DT_F * x[r];
            y[r] = x[r] + w[r];
        }
        // term 2
        f32x4 v4;
        matvec(w, v4);
#pragma unroll
        for (int r = 0; r < 4; ++r) {
            w[r] = (mdt[r] * v4[r] - DT_F * w[r]) * 0.5f;
            y[r] += w[r];
        }
        // term 3
        matvec(w, v4);
#pragma unroll
        for (int r = 0; r < 4; ++r) {
            w[r] = (mdt[r] * v4[r] - DT_F * w[r]) * (1.0f / 3.0f);
            y[r] += w[r];
        }
#pragma unroll
        for (int r = 0; r < 4; ++r) x[r] = y[r];
    }
}

extern "C" void kernel_launch(void* const* d_in, const int* in_sizes, int n_in,
                              void* d_out, int out_size, void* d_ws, size_t ws_size,
                              hipStream_t stream) {
    const float* x0 = (const float*)d_in[0];   // (256, 64) f32
    const float* W  = (const float*)d_in[1];   // (64, 64)  f32
    const float* b  = (const float*)d_in[2];   // (64,)     f32
    float* out = (float*)d_out;                // (256, 100, 64) f32

    int batch = in_sizes[0] / DD;
    if (batch <= 0 || batch > BATCH_MAX) batch = BATCH_MAX;
    const int wgs = (batch + BT - 1) / BT;     // 16 workgroups x 16 chains
    abla_kernel<<<wgs, 256, 0, stream>>>(x0, W, b, out);
}